// Round 4
// baseline (255.956 us; speedup 1.0000x reference)
//
#include <hip/hip_runtime.h>
#include <math.h>

// Problem constants (fixed by setup_inputs)
#define HD 32
#define BB 256
#define SS 4096
#define BLK 256           // threads per block (4 independent waves)
#define POSB 256          // positions per chunk
#define GRP 4             // chunks per block (pipelined)
#define NWREC 16          // per-wave records per row (4 blocks x 4 waves)
#define PREC 36           // floats per record: [L, pad3, y[32]]

typedef short bf16x8 __attribute__((ext_vector_type(8)));
typedef float f32x4 __attribute__((ext_vector_type(4)));

__device__ __forceinline__ float tanh_fast(float x) {
  float e = __builtin_amdgcn_exp2f(x * 2.8853900817779268f); // 2*log2(e)
  return 1.0f - 2.0f * __builtin_amdgcn_rcpf(e + 1.0f);
}
__device__ __forceinline__ float exp_fast(float x) {
  return __builtin_amdgcn_exp2f(x * 1.4426950408889634f);    // log2(e)
}
__device__ __forceinline__ short bf16_trunc(float x) {      // truncate to bf16
  return (short)(__float_as_uint(x) >> 16);
}
__device__ __forceinline__ float hi_part(float x) {         // fp32, low16=0
  return __uint_as_float(__float_as_uint(x) & 0xffff0000u);
}

// Phase 0 (tiny): precompute qb[b][h] = bq+bk + fh[b]@Wq once; pre-pack WkT
// hi/lo bf16 fragments to global (L2-resident for p1).
__global__ void __launch_bounds__(256) bahdanau_p0(
    const float* __restrict__ fh, const float* __restrict__ Wq,
    const float* __restrict__ bq, const float* __restrict__ bk,
    const float* __restrict__ Wk, float* __restrict__ qbP,
    short* __restrict__ wkH, short* __restrict__ wkL) {
  const int tid = threadIdx.x;
  if (blockIdx.x == 32) {  // pack Wk transposed + hi/lo split
    float4 w4 = ((const float4*)Wk)[tid];
    const int k = tid >> 3, h0 = (tid & 7) * 4;
    const float v[4] = {w4.x, w4.y, w4.z, w4.w};
#pragma unroll
    for (int i = 0; i < 4; i++) {
      const float hf = hi_part(v[i]);
      wkH[(h0 + i) * HD + k] = bf16_trunc(v[i]);
      wkL[(h0 + i) * HD + k] = bf16_trunc(v[i] - hf);
    }
  } else {
    const int b = blockIdx.x * 8 + (tid >> 5);
    const int h = tid & 31;
    float acc = bq[h] + bk[h];
    const float* fhb = fh + b * HD;
#pragma unroll
    for (int j = 0; j < HD; j++) acc = fmaf(fhb[j], Wq[j * HD + h], acc);
    qbP[b * HD + h] = acc;
  }
}

// Phase 1: one block per (row b, group of 4 chunks = 1024 positions).
// 4 independent waves, no LDS, no barriers. Named-register PING-PONG
// software pipeline: while computing chunk c the 8 dwordx4 loads of chunk
// c+1 are in flight (counted vmcnt, never a full drain mid-loop). R1's
// array-indexed attempt at this spilled to scratch (+103 MB); all buffer
// registers here are STATIC names, stages fully unrolled.
__global__ void __launch_bounds__(BLK, 4) bahdanau_p1(
    const float* __restrict__ lstm, const float* __restrict__ qbP,
    const short* __restrict__ wkH, const short* __restrict__ wkL,
    const float* __restrict__ Wv, const float* __restrict__ bv,
    float* __restrict__ scores_out, float* __restrict__ partials) {
  const int tid = threadIdx.x;
  const int b = blockIdx.x >> 2;          // / 4 groups
  const int grp = blockIdx.x & 3;
  const int base = grp * (GRP * POSB);    // 1024 positions per block
  const int lane = tid & 63, w = tid >> 6;
  const int col = lane & 15, quad = lane >> 4;

  const float* rp =
      lstm + ((size_t)b * SS + base + w * 64 + col) * HD + quad * 8;

  float4 pa0, pb0, pa1, pb1, pa2, pb2, pa3, pb3;  // ping
  float4 qa0, qb0_, qa1, qb1_, qa2, qb2_, qa3, qb3_;  // pong

#define LOADC(cc, A0, B0, A1, B1, A2, B2, A3, B3)                              \
  {                                                                            \
    const float* p_ = rp + (size_t)(cc) * (POSB * HD);                         \
    A0 = ((const float4*)(p_ + 0 * 16 * HD))[0];                               \
    B0 = ((const float4*)(p_ + 0 * 16 * HD))[1];                               \
    A1 = ((const float4*)(p_ + 1 * 16 * HD))[0];                               \
    B1 = ((const float4*)(p_ + 1 * 16 * HD))[1];                               \
    A2 = ((const float4*)(p_ + 2 * 16 * HD))[0];                               \
    B2 = ((const float4*)(p_ + 2 * 16 * HD))[1];                               \
    A3 = ((const float4*)(p_ + 3 * 16 * HD))[0];                               \
    B3 = ((const float4*)(p_ + 3 * 16 * HD))[1];                               \
  }

  // chunk 0 loads first (long pole), then the L2-hot aux loads
  LOADC(0, pa0, pb0, pa1, pb1, pa2, pb2, pa3, pb3)

  // A-frags: lane holds A[row=col][k=quad*8+j] = WkT[h=col][k] (and h=col+16)
  const bf16x8 Ah0 = *(const bf16x8*)&wkH[col * HD + quad * 8];
  const bf16x8 Al0 = *(const bf16x8*)&wkL[col * HD + quad * 8];
  const bf16x8 Ah1 = *(const bf16x8*)&wkH[(16 + col) * HD + quad * 8];
  const bf16x8 Al1 = *(const bf16x8*)&wkL[(16 + col) * HD + quad * 8];
  const float4 qbA = ((const float4*)(qbP + b * HD))[quad];
  const float4 qbB = ((const float4*)(qbP + b * HD))[quad + 4];
  const float4 wvA = ((const float4*)Wv)[quad];
  const float4 wvB = ((const float4*)Wv)[quad + 4];
  const float bv0 = bv[0];

  float lAcc = 0.f;
  float yp[8];
#pragma unroll
  for (int j = 0; j < 8; j++) yp[j] = 0.f;

  const size_t srow = (size_t)b * SS + base;

#define MT_STEP(cc, mt, XA, XB)                                                \
  {                                                                            \
    const float xs[8] = {XA.x, XA.y, XA.z, XA.w, XB.x, XB.y, XB.z, XB.w};      \
    bf16x8 Bh, Bl;                                                             \
    _Pragma("unroll") for (int j = 0; j < 8; j++) {                            \
      const float hf = hi_part(xs[j]);                                         \
      Bh[j] = bf16_trunc(xs[j]);                                               \
      Bl[j] = bf16_trunc(xs[j] - hf);                                          \
    }                                                                          \
    f32x4 c0 = {0.f, 0.f, 0.f, 0.f}, c1 = {0.f, 0.f, 0.f, 0.f};                \
    c0 = __builtin_amdgcn_mfma_f32_16x16x32_bf16(Ah0, Bh, c0, 0, 0, 0);        \
    c1 = __builtin_amdgcn_mfma_f32_16x16x32_bf16(Ah1, Bh, c1, 0, 0, 0);        \
    c0 = __builtin_amdgcn_mfma_f32_16x16x32_bf16(Al0, Bh, c0, 0, 0, 0);        \
    c1 = __builtin_amdgcn_mfma_f32_16x16x32_bf16(Al1, Bh, c1, 0, 0, 0);        \
    c0 = __builtin_amdgcn_mfma_f32_16x16x32_bf16(Ah0, Bl, c0, 0, 0, 0);        \
    c1 = __builtin_amdgcn_mfma_f32_16x16x32_bf16(Ah1, Bl, c1, 0, 0, 0);        \
    const float t0 = tanh_fast(c0[0] + qbA.x) * wvA.x;                         \
    const float t1 = tanh_fast(c0[1] + qbA.y) * wvA.y;                         \
    const float t2 = tanh_fast(c0[2] + qbA.z) * wvA.z;                         \
    const float t3 = tanh_fast(c0[3] + qbA.w) * wvA.w;                         \
    const float t4 = tanh_fast(c1[0] + qbB.x) * wvB.x;                         \
    const float t5 = tanh_fast(c1[1] + qbB.y) * wvB.y;                         \
    const float t6 = tanh_fast(c1[2] + qbB.z) * wvB.z;                         \
    const float t7 = tanh_fast(c1[3] + qbB.w) * wvB.w;                         \
    float t = ((t0 + t1) + (t2 + t3)) + ((t4 + t5) + (t6 + t7));               \
    t += __shfl_xor(t, 16, 64);                                                \
    t += __shfl_xor(t, 32, 64);                                                \
    const float e_m = exp_fast(t + bv0); /* e for pos=col, in every lane */    \
    if (lane < 16)                                                             \
      scores_out[srow + (cc)*POSB + w * 64 + (mt)*16 + lane] = e_m;            \
    lAcc += (lane < 16) ? e_m : 0.f;                                           \
    _Pragma("unroll") for (int j = 0; j < 8; j++)                              \
        yp[j] = fmaf(e_m, xs[j], yp[j]);                                       \
  }

#define CHUNK(cc, A0, B0, A1, B1, A2, B2, A3, B3)                              \
  MT_STEP(cc, 0, A0, B0)                                                       \
  MT_STEP(cc, 1, A1, B1)                                                       \
  MT_STEP(cc, 2, A2, B2)                                                       \
  MT_STEP(cc, 3, A3, B3)

  // ---- pipeline: issue next chunk's loads, then compute current chunk
  LOADC(1, qa0, qb0_, qa1, qb1_, qa2, qb2_, qa3, qb3_)
  CHUNK(0, pa0, pb0, pa1, pb1, pa2, pb2, pa3, pb3)
  LOADC(2, pa0, pb0, pa1, pb1, pa2, pb2, pa3, pb3)
  CHUNK(1, qa0, qb0_, qa1, qb1_, qa2, qb2_, qa3, qb3_)
  LOADC(3, qa0, qb0_, qa1, qb1_, qa2, qb2_, qa3, qb3_)
  CHUNK(2, pa0, pb0, pa1, pb1, pa2, pb2, pa3, pb3)
  CHUNK(3, qa0, qb0_, qa1, qb1_, qa2, qb2_, qa3, qb3_)
#undef CHUNK
#undef MT_STEP
#undef LOADC

  // reduce y over the 16 cols of this quad's h-slice (within-wave only)
#pragma unroll
  for (int j = 0; j < 8; j++) {
    yp[j] += __shfl_xor(yp[j], 1, 64);
    yp[j] += __shfl_xor(yp[j], 2, 64);
    yp[j] += __shfl_xor(yp[j], 4, 64);
    yp[j] += __shfl_xor(yp[j], 8, 64);
  }
  lAcc += __shfl_xor(lAcc, 1, 64);
  lAcc += __shfl_xor(lAcc, 2, 64);
  lAcc += __shfl_xor(lAcc, 4, 64);
  lAcc += __shfl_xor(lAcc, 8, 64);

  float* rec = partials + (size_t)(blockIdx.x * 4 + w) * PREC;
  if (col == 0) {  // lanes 0,16,32,48 own h = quad*8 .. +8
    const float4 y0 = {yp[0], yp[1], yp[2], yp[3]};
    const float4 y1 = {yp[4], yp[5], yp[6], yp[7]};
    ((float4*)(rec + 4))[quad * 2] = y0;
    ((float4*)(rec + 4))[quad * 2 + 1] = y1;
  }
  if (lane == 0) rec[0] = lAcc;
}

// Phase 2: 1024 blocks; block scales 1024 consecutive scores (float4/thread)
// of row b = blk>>2. Sub-block 0 also builds ctx = (Y@Wk)/L + bk.
__global__ void __launch_bounds__(BLK) bahdanau_p2(
    const float* __restrict__ partials, const float* __restrict__ Wk,
    const float* __restrict__ bk, float* __restrict__ ctx_out,
    float* __restrict__ scores) {
  const int blk = blockIdx.x;
  const int b = blk >> 2;
  const int tid = threadIdx.x;
  __shared__ float sY[HD];

  float L = 0.f;
#pragma unroll
  for (int c = 0; c < NWREC; c++)
    L += partials[(size_t)(b * NWREC + c) * PREC];
  const float invL = __builtin_amdgcn_rcpf(L);

  if ((blk & 3) == 0) {   // block-uniform branch: barrier inside is legal
    if (tid < HD) {
      float y = 0.f;
#pragma unroll
      for (int c = 0; c < NWREC; c++)
        y += partials[(size_t)(b * NWREC + c) * PREC + 4 + tid];
      sY[tid] = y;
    }
    __syncthreads();
    if (tid < HD) {
      float cv = bk[tid] * L;
#pragma unroll
      for (int j = 0; j < HD; j++) cv = fmaf(sY[j], Wk[j * HD + tid], cv);
      ctx_out[b * HD + tid] = cv * invL;
    }
  }

  float4* srow = (float4*)(scores + (size_t)b * SS + (blk & 3) * 1024);
  float4 s = srow[tid];
  s.x *= invL; s.y *= invL; s.z *= invL; s.w *= invL;
  srow[tid] = s;
}

extern "C" void kernel_launch(void* const* d_in, const int* in_sizes, int n_in,
                              void* d_out, int out_size, void* d_ws,
                              size_t ws_size, hipStream_t stream) {
  const float* lstm = (const float*)d_in[0];
  const float* fh   = (const float*)d_in[1];
  const float* Wq   = (const float*)d_in[2];
  const float* bq   = (const float*)d_in[3];
  const float* Wk   = (const float*)d_in[4];
  const float* bk   = (const float*)d_in[5];
  const float* Wv   = (const float*)d_in[6];
  const float* bv   = (const float*)d_in[7];

  float* out = (float*)d_out;
  float* ctx_out = out;           // context: B*H floats
  float* scores = out + BB * HD;  // att_weights region (e then normalized)

  // workspace carve (all 16B-aligned):
  float* partials = (float*)d_ws;                          // 4096*36*4 B
  short* wkH = (short*)((char*)d_ws + (size_t)BB * NWREC * PREC * 4);
  short* wkL = wkH + HD * HD;                              // +2 KB
  float* qbP = (float*)(wkL + HD * HD);                    // +2 KB

  bahdanau_p0<<<33, 256, 0, stream>>>(fh, Wq, bq, bk, Wk, qbP, wkH, wkL);
  bahdanau_p1<<<BB * 4, BLK, 0, stream>>>(lstm, qbP, wkH, wkL, Wv, bv,
                                          scores, partials);
  bahdanau_p2<<<BB * 4, BLK, 0, stream>>>(partials, Wk, bk, ctx_out, scores);
}

// Round 5
// 209.192 us; speedup vs baseline: 1.2235x; 1.2235x over previous
//
#include <hip/hip_runtime.h>
#include <math.h>

// Problem constants (fixed by setup_inputs)
#define HD 32
#define BB 256
#define SS 4096
#define BLK 256           // threads per block (4 independent waves)
#define NWREC 32          // per-wave records per row (8 blocks x 4 waves)
#define PREC 36           // floats per record: [L, pad3, y[32]]

typedef short bf16x8 __attribute__((ext_vector_type(8)));
typedef float f32x4 __attribute__((ext_vector_type(4)));

__device__ __forceinline__ float tanh_fast(float x) {
  float e = __builtin_amdgcn_exp2f(x * 2.8853900817779268f); // 2*log2(e)
  return 1.0f - 2.0f * __builtin_amdgcn_rcpf(e + 1.0f);
}
__device__ __forceinline__ float exp_fast(float x) {
  return __builtin_amdgcn_exp2f(x * 1.4426950408889634f);    // log2(e)
}
__device__ __forceinline__ short bf16_trunc(float x) {      // truncate to bf16
  return (short)(__float_as_uint(x) >> 16);
}
__device__ __forceinline__ float hi_part(float x) {         // fp32, low16=0
  return __uint_as_float(__float_as_uint(x) & 0xffff0000u);
}

// Phase 0 (tiny): precompute qb[b][h] = bq+bk + fh[b]@Wq once; pre-pack WkT
// hi/lo bf16 fragments to global (L2-resident for p1).
__global__ void __launch_bounds__(256) bahdanau_p0(
    const float* __restrict__ fh, const float* __restrict__ Wq,
    const float* __restrict__ bq, const float* __restrict__ bk,
    const float* __restrict__ Wk, float* __restrict__ qbP,
    short* __restrict__ wkH, short* __restrict__ wkL) {
  const int tid = threadIdx.x;
  if (blockIdx.x == 32) {  // pack Wk transposed + hi/lo split
    float4 w4 = ((const float4*)Wk)[tid];
    const int k = tid >> 3, h0 = (tid & 7) * 4;
    const float v[4] = {w4.x, w4.y, w4.z, w4.w};
#pragma unroll
    for (int i = 0; i < 4; i++) {
      const float hf = hi_part(v[i]);
      wkH[(h0 + i) * HD + k] = bf16_trunc(v[i]);
      wkL[(h0 + i) * HD + k] = bf16_trunc(v[i] - hf);
    }
  } else {
    const int b = blockIdx.x * 8 + (tid >> 5);
    const int h = tid & 31;
    float acc = bq[h] + bk[h];
    const float* fhb = fh + b * HD;
#pragma unroll
    for (int j = 0; j < HD; j++) acc = fmaf(fhb[j], Wq[j * HD + h], acc);
    qbP[b * HD + h] = acc;
  }
}

// Phase 1: 2048 blocks (8 per row), 4 INDEPENDENT waves (no barriers).
// In-flight data lives in LDS via global_load_lds (zero VGPR cost — R1/R4's
// register pipelines both spilled). Each wave: 3 private 4KB buffers, 4
// tiles of 32 positions, depth-2 prefetch with counted vmcnt (in-order
// retirement makes the counts exact; score stores are DEFERRED so no other
// vm ops pollute the counter). LDS is XOR-swizzled on the READ side with
// the inverse swizzle pre-applied to the GLOBAL SOURCE address (gload_lds
// writes linearly: swizzle must be source+read, never dest).
__global__ void __launch_bounds__(BLK, 3) bahdanau_p1(
    const float* __restrict__ lstm, const float* __restrict__ qbP,
    const short* __restrict__ wkH, const short* __restrict__ wkL,
    const float* __restrict__ Wv, const float* __restrict__ bv,
    float* __restrict__ scores_out, float* __restrict__ partials) {
  __shared__ __align__(16) float sX[4 * 3 * 1024];  // 4 waves x 3 x 4KB
  const int tid = threadIdx.x;
  const int b = blockIdx.x >> 3;
  const int grp = blockIdx.x & 7;        // 512-position group
  const int lane = tid & 63, w = tid >> 6;
  const int col = lane & 15, quad = lane >> 4;

  // ---- aux loads FIRST: oldest vmcnt entries, retired by the first wait
  const bf16x8 Ah0 = *(const bf16x8*)&wkH[col * HD + quad * 8];
  const bf16x8 Al0 = *(const bf16x8*)&wkL[col * HD + quad * 8];
  const bf16x8 Ah1 = *(const bf16x8*)&wkH[(16 + col) * HD + quad * 8];
  const bf16x8 Al1 = *(const bf16x8*)&wkL[(16 + col) * HD + quad * 8];
  const float4 qbA = ((const float4*)(qbP + b * HD))[quad];
  const float4 qbB = ((const float4*)(qbP + b * HD))[quad + 4];
  const float4 wvA = ((const float4*)Wv)[quad];
  const float4 wvB = ((const float4*)Wv)[quad + 4];
  const float bv0 = bv[0];

  char* wlds = (char*)sX + w * 12288;    // this wave's 3 buffers
  // global source with inverse read-swizzle pre-applied (16B granules):
  // LDS[c] must hold G[c ^ ((c>>3)&7)]; per-instruction dest granule is
  // i*64+lane, and i*64 is 0 mod 8, so src granule = i*64 + (lane^((lane>>3)&7)).
  const char* gw =
      (const char*)(lstm + ((size_t)b * SS + grp * 512 + w * 128) * HD) +
      ((lane ^ ((lane >> 3) & 7)) << 4);
  // reader byte offset inside a buffer for (s, col, quad), XOR-swizzled:
  const int rOff0 = (col * 128 + quad * 32) ^ ((col & 7) << 4);

#define STAGE(t, buf)                                                          \
  {                                                                            \
    _Pragma("unroll") for (int i = 0; i < 4; i++)                              \
        __builtin_amdgcn_global_load_lds(                                      \
            (const __attribute__((address_space(1))) void*)(gw + (t)*4096 +    \
                                                            i * 1024),         \
            (__attribute__((address_space(3))) void*)(wlds + (buf)*4096 +      \
                                                      i * 1024),               \
            16, 0, 0);                                                         \
  }
#define WAITV(n)                                                               \
  asm volatile("s_waitcnt vmcnt(" #n ")" ::: "memory");                        \
  __builtin_amdgcn_sched_barrier(0);

  float lAcc = 0.f;
  float yp[8];
#pragma unroll
  for (int j = 0; j < 8; j++) yp[j] = 0.f;
  float e0, e1, e2, e3, e4, e5, e6, e7;

#define MT_STEP(buf, s, EOUT)                                                  \
  {                                                                            \
    const char* pr_ = wlds + (buf)*4096 + (s)*2048;                            \
    const float4 XA = *(const float4*)(pr_ + rOff0);                           \
    const float4 XB = *(const float4*)(pr_ + (rOff0 ^ 16));                    \
    const float xs[8] = {XA.x, XA.y, XA.z, XA.w, XB.x, XB.y, XB.z, XB.w};      \
    bf16x8 Bh, Bl;                                                             \
    _Pragma("unroll") for (int j = 0; j < 8; j++) {                            \
      const float hf = hi_part(xs[j]);                                         \
      Bh[j] = bf16_trunc(xs[j]);                                               \
      Bl[j] = bf16_trunc(xs[j] - hf);                                          \
    }                                                                          \
    f32x4 c0 = {0.f, 0.f, 0.f, 0.f}, c1 = {0.f, 0.f, 0.f, 0.f};                \
    c0 = __builtin_amdgcn_mfma_f32_16x16x32_bf16(Ah0, Bh, c0, 0, 0, 0);        \
    c1 = __builtin_amdgcn_mfma_f32_16x16x32_bf16(Ah1, Bh, c1, 0, 0, 0);        \
    c0 = __builtin_amdgcn_mfma_f32_16x16x32_bf16(Al0, Bh, c0, 0, 0, 0);        \
    c1 = __builtin_amdgcn_mfma_f32_16x16x32_bf16(Al1, Bh, c1, 0, 0, 0);        \
    c0 = __builtin_amdgcn_mfma_f32_16x16x32_bf16(Ah0, Bl, c0, 0, 0, 0);        \
    c1 = __builtin_amdgcn_mfma_f32_16x16x32_bf16(Ah1, Bl, c1, 0, 0, 0);        \
    const float t0 = tanh_fast(c0[0] + qbA.x) * wvA.x;                         \
    const float t1 = tanh_fast(c0[1] + qbA.y) * wvA.y;                         \
    const float t2 = tanh_fast(c0[2] + qbA.z) * wvA.z;                         \
    const float t3 = tanh_fast(c0[3] + qbA.w) * wvA.w;                         \
    const float t4 = tanh_fast(c1[0] + qbB.x) * wvB.x;                         \
    const float t5 = tanh_fast(c1[1] + qbB.y) * wvB.y;                         \
    const float t6 = tanh_fast(c1[2] + qbB.z) * wvB.z;                         \
    const float t7 = tanh_fast(c1[3] + qbB.w) * wvB.w;                         \
    float t = ((t0 + t1) + (t2 + t3)) + ((t4 + t5) + (t6 + t7));               \
    t += __shfl_xor(t, 16, 64);                                                \
    t += __shfl_xor(t, 32, 64);                                                \
    const float e_m = exp_fast(t + bv0); /* e for pos=col, in every lane */    \
    EOUT = e_m;                                                                \
    lAcc += (lane < 16) ? e_m : 0.f;                                           \
    _Pragma("unroll") for (int j = 0; j < 8; j++)                              \
        yp[j] = fmaf(e_m, xs[j], yp[j]);                                       \
  }

  // ---- pipeline: depth-2 prefetch, counted vmcnt, never 0 mid-loop.
  STAGE(0, 0)
  STAGE(1, 1)
  STAGE(2, 2)
  WAITV(8)          // S0 done (aux + S0 are the oldest; S1,S2 stay in flight)
  MT_STEP(0, 0, e0)
  MT_STEP(0, 1, e1)
  STAGE(3, 0)       // buf0 free after C0
  WAITV(8)          // S1 done; S2,S3 in flight
  MT_STEP(1, 0, e2)
  MT_STEP(1, 1, e3)
  WAITV(4)          // S2 done; S3 in flight
  MT_STEP(2, 0, e4)
  MT_STEP(2, 1, e5)
  WAITV(0)          // S3 done (tail only)
  MT_STEP(0, 0, e6)
  MT_STEP(0, 1, e7)
#undef MT_STEP
#undef STAGE
#undef WAITV

  // ---- deferred score stores (kept out of the vmcnt-counted region)
  if (lane < 16) {
    float* sp = scores_out + (size_t)b * SS + grp * 512 + w * 128 + lane;
    sp[0] = e0;  sp[16] = e1;  sp[32] = e2;  sp[48] = e3;
    sp[64] = e4; sp[80] = e5;  sp[96] = e6;  sp[112] = e7;
  }

  // reduce y over the 16 cols of this quad's h-slice (within-wave only)
#pragma unroll
  for (int j = 0; j < 8; j++) {
    yp[j] += __shfl_xor(yp[j], 1, 64);
    yp[j] += __shfl_xor(yp[j], 2, 64);
    yp[j] += __shfl_xor(yp[j], 4, 64);
    yp[j] += __shfl_xor(yp[j], 8, 64);
  }
  lAcc += __shfl_xor(lAcc, 1, 64);
  lAcc += __shfl_xor(lAcc, 2, 64);
  lAcc += __shfl_xor(lAcc, 4, 64);
  lAcc += __shfl_xor(lAcc, 8, 64);

  float* rec = partials + (size_t)(blockIdx.x * 4 + w) * PREC;
  if (col == 0) {  // lanes 0,16,32,48 own h = quad*8 .. +8
    const float4 y0 = {yp[0], yp[1], yp[2], yp[3]};
    const float4 y1 = {yp[4], yp[5], yp[6], yp[7]};
    ((float4*)(rec + 4))[quad * 2] = y0;
    ((float4*)(rec + 4))[quad * 2 + 1] = y1;
  }
  if (lane == 0) rec[0] = lAcc;
}

// Phase 2: 1024 blocks; block scales 1024 consecutive scores (float4/thread)
// of row b = blk>>2. Sub-block 0 also builds ctx = (Y@Wk)/L + bk.
__global__ void __launch_bounds__(BLK) bahdanau_p2(
    const float* __restrict__ partials, const float* __restrict__ Wk,
    const float* __restrict__ bk, float* __restrict__ ctx_out,
    float* __restrict__ scores) {
  const int blk = blockIdx.x;
  const int b = blk >> 2;
  const int tid = threadIdx.x;
  __shared__ float sY[HD];

  float L = 0.f;
#pragma unroll 8
  for (int c = 0; c < NWREC; c++)
    L += partials[(size_t)(b * NWREC + c) * PREC];
  const float invL = __builtin_amdgcn_rcpf(L);

  if ((blk & 3) == 0) {   // block-uniform branch: barrier inside is legal
    if (tid < HD) {
      float y = 0.f;
#pragma unroll 8
      for (int c = 0; c < NWREC; c++)
        y += partials[(size_t)(b * NWREC + c) * PREC + 4 + tid];
      sY[tid] = y;
    }
    __syncthreads();
    if (tid < HD) {
      float cv = bk[tid] * L;
#pragma unroll
      for (int j = 0; j < HD; j++) cv = fmaf(sY[j], Wk[j * HD + tid], cv);
      ctx_out[b * HD + tid] = cv * invL;
    }
  }

  float4* srow = (float4*)(scores + (size_t)b * SS + (blk & 3) * 1024);
  float4 s = srow[tid];
  s.x *= invL; s.y *= invL; s.z *= invL; s.w *= invL;
  srow[tid] = s;
}

extern "C" void kernel_launch(void* const* d_in, const int* in_sizes, int n_in,
                              void* d_out, int out_size, void* d_ws,
                              size_t ws_size, hipStream_t stream) {
  const float* lstm = (const float*)d_in[0];
  const float* fh   = (const float*)d_in[1];
  const float* Wq   = (const float*)d_in[2];
  const float* bq   = (const float*)d_in[3];
  const float* Wk   = (const float*)d_in[4];
  const float* bk   = (const float*)d_in[5];
  const float* Wv   = (const float*)d_in[6];
  const float* bv   = (const float*)d_in[7];

  float* out = (float*)d_out;
  float* ctx_out = out;           // context: B*H floats
  float* scores = out + BB * HD;  // att_weights region (e then normalized)

  // workspace carve (all 16B-aligned):
  float* partials = (float*)d_ws;                          // 256*32*36*4 B
  short* wkH = (short*)((char*)d_ws + (size_t)BB * NWREC * PREC * 4);
  short* wkL = wkH + HD * HD;                              // +2 KB
  float* qbP = (float*)(wkL + HD * HD);                    // +2 KB

  bahdanau_p0<<<33, 256, 0, stream>>>(fh, Wq, bq, bk, Wk, qbP, wkH, wkL);
  bahdanau_p1<<<BB * 8, BLK, 0, stream>>>(lstm, qbP, wkH, wkL, Wv, bv,
                                          scores, partials);
  bahdanau_p2<<<BB * 4, BLK, 0, stream>>>(partials, Wk, bk, ctx_out, scores);
}

// Round 6
// 206.088 us; speedup vs baseline: 1.2420x; 1.0151x over previous
//
#include <hip/hip_runtime.h>
#include <math.h>

// Problem constants (fixed by setup_inputs)
#define HD 32
#define BB 256
#define SS 4096
#define BLK 256           // threads per block (4 waves)
#define NWREC 32          // records per row (32 blocks/row, 1 per block)
#define PREC 36           // floats per record: [L, pad3, y[32]]

typedef short bf16x8 __attribute__((ext_vector_type(8)));
typedef float f32x4 __attribute__((ext_vector_type(4)));

__device__ __forceinline__ float tanh_fast(float x) {
  float e = __builtin_amdgcn_exp2f(x * 2.8853900817779268f); // 2*log2(e)
  return 1.0f - 2.0f * __builtin_amdgcn_rcpf(e + 1.0f);
}
__device__ __forceinline__ float exp_fast(float x) {
  return __builtin_amdgcn_exp2f(x * 1.4426950408889634f);    // log2(e)
}
__device__ __forceinline__ short bf16_trunc(float x) {      // truncate to bf16
  return (short)(__float_as_uint(x) >> 16);
}
__device__ __forceinline__ float hi_part(float x) {         // fp32, low16=0
  return __uint_as_float(__float_as_uint(x) & 0xffff0000u);
}

// Phase 0 (tiny): precompute qb[b][h] = bq+bk + fh[b]@Wq once; pre-pack WkT
// hi/lo bf16 fragments to global (L2-resident for p1).
__global__ void __launch_bounds__(256) bahdanau_p0(
    const float* __restrict__ fh, const float* __restrict__ Wq,
    const float* __restrict__ bq, const float* __restrict__ bk,
    const float* __restrict__ Wk, float* __restrict__ qbP,
    short* __restrict__ wkH, short* __restrict__ wkL) {
  const int tid = threadIdx.x;
  if (blockIdx.x == 32) {  // pack Wk transposed + hi/lo split
    float4 w4 = ((const float4*)Wk)[tid];
    const int k = tid >> 3, h0 = (tid & 7) * 4;
    const float v[4] = {w4.x, w4.y, w4.z, w4.w};
#pragma unroll
    for (int i = 0; i < 4; i++) {
      const float hf = hi_part(v[i]);
      wkH[(h0 + i) * HD + k] = bf16_trunc(v[i]);
      wkL[(h0 + i) * HD + k] = bf16_trunc(v[i] - hf);
    }
  } else {
    const int b = blockIdx.x * 8 + (tid >> 5);
    const int h = tid & 31;
    float acc = bq[h] + bk[h];
    const float* fhb = fh + b * HD;
#pragma unroll
    for (int j = 0; j < HD; j++) acc = fmaf(fhb[j], Wq[j * HD + h], acc);
    qbP[b * HD + h] = acc;
  }
}

// Phase 1 (R6: MAX OCCUPANCY). 8192 blocks x 4 waves; each wave owns only
// 32 positions (2 MT steps, 4 upfront dwordx4 = 16 X-VGPRs). Five prior
// structures all pinned p1 at ~46us with 12 waves/CU; achieved BW matched
// 6.3 TB/s x (resident/32). So: shrink per-wave state, cap VGPR via
// __launch_bounds__(256,5) -> ~20 waves/CU, and let TLP hide all latency
// (HBM, shfl, TRANS). Math is bit-identical to the R3/R5 passing kernels.
__global__ void __launch_bounds__(BLK, 5) bahdanau_p1(
    const float* __restrict__ lstm, const float* __restrict__ qbP,
    const short* __restrict__ wkH, const short* __restrict__ wkL,
    const float* __restrict__ Wv, const float* __restrict__ bv,
    float* __restrict__ scores_out, float* __restrict__ partials) {
  __shared__ float sYp[4][HD];
  __shared__ float sRedL[4];
  const int tid = threadIdx.x;
  const int b = blockIdx.x >> 5;        // 32 blocks per row
  const int seg = blockIdx.x & 31;      // 128-position segment
  const int lane = tid & 63, w = tid >> 6;
  const int col = lane & 15, quad = lane >> 4;

  // ---- X loads first (HBM long pole): 4 x dwordx4, no dependent use
  const float* rp =
      lstm + ((size_t)b * SS + seg * 128 + w * 32 + col) * HD + quad * 8;
  const float4 xa0 = ((const float4*)(rp + 0 * 16 * HD))[0];
  const float4 xb0 = ((const float4*)(rp + 0 * 16 * HD))[1];
  const float4 xa1 = ((const float4*)(rp + 1 * 16 * HD))[0];
  const float4 xb1 = ((const float4*)(rp + 1 * 16 * HD))[1];

  // ---- aux (L2-hot after first few blocks)
  const bf16x8 Ah0 = *(const bf16x8*)&wkH[col * HD + quad * 8];
  const bf16x8 Al0 = *(const bf16x8*)&wkL[col * HD + quad * 8];
  const bf16x8 Ah1 = *(const bf16x8*)&wkH[(16 + col) * HD + quad * 8];
  const bf16x8 Al1 = *(const bf16x8*)&wkL[(16 + col) * HD + quad * 8];
  const float4 qbA = ((const float4*)(qbP + b * HD))[quad];
  const float4 qbB = ((const float4*)(qbP + b * HD))[quad + 4];
  const float4 wvA = ((const float4*)Wv)[quad];
  const float4 wvB = ((const float4*)Wv)[quad + 4];
  const float bv0 = bv[0];

  float lAcc = 0.f;
  float yp[8];
#pragma unroll
  for (int j = 0; j < 8; j++) yp[j] = 0.f;

  const size_t srow = (size_t)b * SS + seg * 128 + w * 32;

#define MT_STEP(mt, XA, XB)                                                    \
  {                                                                            \
    const float xs[8] = {XA.x, XA.y, XA.z, XA.w, XB.x, XB.y, XB.z, XB.w};      \
    bf16x8 Bh, Bl;                                                             \
    _Pragma("unroll") for (int j = 0; j < 8; j++) {                            \
      const float hf = hi_part(xs[j]);                                         \
      Bh[j] = bf16_trunc(xs[j]);                                               \
      Bl[j] = bf16_trunc(xs[j] - hf);                                          \
    }                                                                          \
    f32x4 c0 = {0.f, 0.f, 0.f, 0.f}, c1 = {0.f, 0.f, 0.f, 0.f};                \
    c0 = __builtin_amdgcn_mfma_f32_16x16x32_bf16(Ah0, Bh, c0, 0, 0, 0);        \
    c1 = __builtin_amdgcn_mfma_f32_16x16x32_bf16(Ah1, Bh, c1, 0, 0, 0);        \
    c0 = __builtin_amdgcn_mfma_f32_16x16x32_bf16(Al0, Bh, c0, 0, 0, 0);        \
    c1 = __builtin_amdgcn_mfma_f32_16x16x32_bf16(Al1, Bh, c1, 0, 0, 0);        \
    c0 = __builtin_amdgcn_mfma_f32_16x16x32_bf16(Ah0, Bl, c0, 0, 0, 0);        \
    c1 = __builtin_amdgcn_mfma_f32_16x16x32_bf16(Ah1, Bl, c1, 0, 0, 0);        \
    float t = tanh_fast(c0[0] + qbA.x) * wvA.x;                                \
    t = fmaf(tanh_fast(c0[1] + qbA.y), wvA.y, t);                              \
    t = fmaf(tanh_fast(c0[2] + qbA.z), wvA.z, t);                              \
    t = fmaf(tanh_fast(c0[3] + qbA.w), wvA.w, t);                              \
    t = fmaf(tanh_fast(c1[0] + qbB.x), wvB.x, t);                              \
    t = fmaf(tanh_fast(c1[1] + qbB.y), wvB.y, t);                              \
    t = fmaf(tanh_fast(c1[2] + qbB.z), wvB.z, t);                              \
    t = fmaf(tanh_fast(c1[3] + qbB.w), wvB.w, t);                              \
    t += __shfl_xor(t, 16, 64);                                                \
    t += __shfl_xor(t, 32, 64);                                                \
    const float e_m = exp_fast(t + bv0); /* e for pos=col, in every lane */    \
    if (lane < 16) scores_out[srow + (mt)*16 + lane] = e_m;                    \
    lAcc += (lane < 16) ? e_m : 0.f;                                           \
    _Pragma("unroll") for (int j = 0; j < 8; j++)                              \
        yp[j] = fmaf(e_m, xs[j], yp[j]);                                       \
  }

  MT_STEP(0, xa0, xb0)
  MT_STEP(1, xa1, xb1)
#undef MT_STEP

  // reduce y over the 16 cols of this quad's h-slice (within-wave)
#pragma unroll
  for (int j = 0; j < 8; j++) {
    yp[j] += __shfl_xor(yp[j], 1, 64);
    yp[j] += __shfl_xor(yp[j], 2, 64);
    yp[j] += __shfl_xor(yp[j], 4, 64);
    yp[j] += __shfl_xor(yp[j], 8, 64);
  }
#pragma unroll
  for (int off = 32; off >= 1; off >>= 1) lAcc += __shfl_xor(lAcc, off, 64);

  if (col == 0) {  // lanes 0,16,32,48 own h = quad*8 .. +8
#pragma unroll
    for (int j = 0; j < 8; j++) sYp[w][quad * 8 + j] = yp[j];
  }
  if (lane == 0) sRedL[w] = lAcc;
  __syncthreads();

  if (tid < HD) {  // one record per block
    float* rec = partials + (size_t)blockIdx.x * PREC;
    rec[4 + tid] = sYp[0][tid] + sYp[1][tid] + sYp[2][tid] + sYp[3][tid];
    if (tid == 0) rec[0] = sRedL[0] + sRedL[1] + sRedL[2] + sRedL[3];
  }
}

// Phase 2: 1024 blocks; block scales 1024 consecutive scores (float4/thread)
// of row b = blk>>2. Sub-block 0 also builds ctx = (Y@Wk)/L + bk.
__global__ void __launch_bounds__(BLK) bahdanau_p2(
    const float* __restrict__ partials, const float* __restrict__ Wk,
    const float* __restrict__ bk, float* __restrict__ ctx_out,
    float* __restrict__ scores) {
  const int blk = blockIdx.x;
  const int b = blk >> 2;
  const int tid = threadIdx.x;
  __shared__ float sY[HD];

  float L = 0.f;
#pragma unroll 8
  for (int c = 0; c < NWREC; c++)
    L += partials[(size_t)(b * NWREC + c) * PREC];
  const float invL = __builtin_amdgcn_rcpf(L);

  if ((blk & 3) == 0) {   // block-uniform branch: barrier inside is legal
    if (tid < HD) {
      float y = 0.f;
#pragma unroll 8
      for (int c = 0; c < NWREC; c++)
        y += partials[(size_t)(b * NWREC + c) * PREC + 4 + tid];
      sY[tid] = y;
    }
    __syncthreads();
    if (tid < HD) {
      float cv = bk[tid] * L;
#pragma unroll
      for (int j = 0; j < HD; j++) cv = fmaf(sY[j], Wk[j * HD + tid], cv);
      ctx_out[b * HD + tid] = cv * invL;
    }
  }

  float4* srow = (float4*)(scores + (size_t)b * SS + (blk & 3) * 1024);
  float4 s = srow[tid];
  s.x *= invL; s.y *= invL; s.z *= invL; s.w *= invL;
  srow[tid] = s;
}

extern "C" void kernel_launch(void* const* d_in, const int* in_sizes, int n_in,
                              void* d_out, int out_size, void* d_ws,
                              size_t ws_size, hipStream_t stream) {
  const float* lstm = (const float*)d_in[0];
  const float* fh   = (const float*)d_in[1];
  const float* Wq   = (const float*)d_in[2];
  const float* bq   = (const float*)d_in[3];
  const float* Wk   = (const float*)d_in[4];
  const float* bk   = (const float*)d_in[5];
  const float* Wv   = (const float*)d_in[6];
  const float* bv   = (const float*)d_in[7];

  float* out = (float*)d_out;
  float* ctx_out = out;           // context: B*H floats
  float* scores = out + BB * HD;  // att_weights region (e then normalized)

  // workspace carve (all 16B-aligned):
  float* partials = (float*)d_ws;                          // 8192*36*4 B
  short* wkH = (short*)((char*)d_ws + (size_t)BB * NWREC * PREC * 4);
  short* wkL = wkH + HD * HD;                              // +2 KB
  float* qbP = (float*)(wkL + HD * HD);                    // +2 KB

  bahdanau_p0<<<33, 256, 0, stream>>>(fh, Wq, bq, bk, Wk, qbP, wkH, wkL);
  bahdanau_p1<<<BB * 32, BLK, 0, stream>>>(lstm, qbP, wkH, wkL, Wv, bv,
                                           scores, partials);
  bahdanau_p2<<<BB * 4, BLK, 0, stream>>>(partials, Wk, bk, ctx_out, scores);
}